// Round 8
// baseline (290.198 us; speedup 1.0000x reference)
//
#include <hip/hip_runtime.h>
#include <cstdint>
#include <cstddef>

// Problem: B=128, S=512, H=512
//   context[b,h] = sum_s softmax_s( sum_k tanh(u[b,s,k]) Ve[k] ) * h[b,s,h]
//   u = h@U1a^T + x@U2^T + (h_last@U1b^T broadcast over s)
// R8: T3-minimum 2-phase dbuf (STAGE-before-compute, one __syncthreads/iter),
//   8 waves x (64x32) wave-tile -> 32-AGPR acc, launch_bounds(512,4) for
//   16 waves/CU. All staging global_load_lds (zero staging VGPRs).

typedef _Float16 h8 __attribute__((ext_vector_type(8)));
typedef float    f4 __attribute__((ext_vector_type(4)));

#define GLOAD16(g, l)                                                          \
  __builtin_amdgcn_global_load_lds(                                            \
      (const __attribute__((address_space(1))) void*)(g),                      \
      (__attribute__((address_space(3))) void*)(l), 16, 0, 0)

__device__ __forceinline__ float fast_tanh(float v) {
  float ex = __expf(2.0f * v);
  return 1.0f - 2.0f / (ex + 1.0f);
}

// ---------------------------------------------------------------------------
// Streaming f32 -> fp16 for BOTH h and x in one launch (grid-stride).
// ---------------------------------------------------------------------------
__global__ __launch_bounds__(256)
void cvt2_kernel(const float* __restrict__ h, const float* __restrict__ x,
                 _Float16* __restrict__ hF, _Float16* __restrict__ xF) {
  const int stride = gridDim.x * 256;
  for (int i = blockIdx.x * 256 + threadIdx.x; i < 8388608; i += stride) {
    const bool isH = i < 4194304;
    const float* p = (isH ? h : x) + ((size_t)(i & 4194303)) * 8;
    _Float16* d = (isH ? hF : xF) + ((size_t)(i & 4194303)) * 8;
    f4 a = *(const f4*)p, b = *(const f4*)(p + 4);
    _Float16 hv[8];
    hv[0]=(_Float16)a[0]; hv[1]=(_Float16)a[1]; hv[2]=(_Float16)a[2]; hv[3]=(_Float16)a[3];
    hv[4]=(_Float16)b[0]; hv[5]=(_Float16)b[1]; hv[6]=(_Float16)b[2]; hv[7]=(_Float16)b[3];
    *(uint4*)d = *(uint4*)hv;
  }
}

// ---------------------------------------------------------------------------
// B image, fragment-ordered for the 8-wave layout.
// Tile (nt, kt) = 16 KB = 1024 chunks of 16B; chunk index within tile:
//   gt = (((kk*4+lhi)*4 + wn)*2 + nf)*16 + l15
//   holds U[nt*128 + wn*32 + nf*16 + l15][kt*64 + (kk*4+lhi)*8 .. +8]
//   U[n][k] = k<512 ? U1[n][k] : U2[n][k-512]
// ---------------------------------------------------------------------------
__global__ void bsetup3_kernel(const float* __restrict__ U1, const float* __restrict__ U2,
                               _Float16* __restrict__ Bimg) {
  int g = blockIdx.x * 256 + threadIdx.x;   // 65536 chunks
  int gt  = g & 1023;
  int kt  = (g >> 10) & 15;
  int nt  = g >> 14;
  int l15 = gt & 15;
  int nf  = (gt >> 4) & 1;
  int wn  = (gt >> 5) & 3;
  int c8  = gt >> 7;                        // kk*4+lhi, 0..7
  int n = nt * 128 + wn * 32 + nf * 16 + l15;
  int k = kt * 64 + c8 * 8;
  const float* p = (k < 512) ? (U1 + (size_t)n * 1024 + k)
                             : (U2 + (size_t)n * 512 + (k - 512));
  f4 a = *(const f4*)p, b = *(const f4*)(p + 4);
  _Float16 hv[8];
  hv[0]=(_Float16)a[0]; hv[1]=(_Float16)a[1]; hv[2]=(_Float16)a[2]; hv[3]=(_Float16)a[3];
  hv[4]=(_Float16)b[0]; hv[5]=(_Float16)b[1]; hv[6]=(_Float16)b[2]; hv[7]=(_Float16)b[3];
  *(uint4*)(Bimg + (size_t)g * 8) = *(uint4*)hv;
}

// ---------------------------------------------------------------------------
// bias[b][n] = sum_h h[b][S-1][h] * U1[n][512+h]   (fp32, exact)
// ---------------------------------------------------------------------------
__global__ void bias_kernel(const float* __restrict__ hT, const float* __restrict__ U1,
                            float* __restrict__ bias) {
  const int b = blockIdx.x, t = threadIdx.x;
  const int l = t & 63, w = t >> 6;
  __shared__ float4 hl[128];
  if (t < 128) hl[t] = *(const float4*)(hT + ((size_t)b * 512 + 511) * 512 + t * 4);
  __syncthreads();
  for (int n = w; n < 512; n += 4) {
    const float4* ur = (const float4*)(U1 + (size_t)n * 1024 + 512);
    float4 u0 = ur[l],      u1 = ur[l + 64];
    float4 h0 = hl[l],      h1 = hl[l + 64];
    float s = u0.x*h0.x + u0.y*h0.y + u0.z*h0.z + u0.w*h0.w
            + u1.x*h1.x + u1.y*h1.y + u1.z*h1.z + u1.w*h1.w;
#pragma unroll
    for (int d = 1; d < 64; d <<= 1) s += __shfl_xor(s, d, 64);
    if (l == 0) bias[(size_t)b * 512 + n] = s;
  }
}

// ---------------------------------------------------------------------------
// Fused GEMM: M=65536, N=512 (4 x BN=128), K=1024, BK=64.
// 512 threads = 8 waves (wm 0..1, wn 0..3), wave tile 64x32 (4x2 frags 16x16x32).
// T3-min loop: STAGE(next) -> compute(cur) -> __syncthreads (vmcnt0 drain has
// a full compute phase of slack). Dbuf 64 KB; 2 blocks/CU; 16 waves/CU.
// ---------------------------------------------------------------------------
__global__ __launch_bounds__(512, 4)
void gemm4_kernel(const _Float16* __restrict__ hF, const _Float16* __restrict__ xF,
                  const _Float16* __restrict__ Bimg, const float* __restrict__ bias,
                  const float* __restrict__ Ve, float* __restrict__ e) {
  // XCD-chunked bijective swizzle (2048 = 8*256): nt-siblings adjacent on one XCD.
  const int bid  = ((int)blockIdx.x & 7) * 256 + ((int)blockIdx.x >> 3);
  const int bm   = bid >> 2;
  const int nt   = bid & 3;
  const int row0 = bm * 128;
  const int bb   = row0 >> 9;
  const int t    = threadIdx.x;
  const int l    = t & 63;
  const int wv   = t >> 6;
  const int wm   = wv >> 2, wn = wv & 3;
  const int l15  = l & 15, lhi = l >> 4;

  __shared__ __align__(16) _Float16 Asm[2][8192];   // 2 x 16 KB
  __shared__ __align__(16) _Float16 Bsm[2][8192];   // 2 x 16 KB

  // A: wave wv stages rows wv*16..+16 (2 insts); source XOR pre-swizzled.
  const int aoff0 = (wv * 16 + (l >> 3)) * 512 + (((l & 7) ^ (l >> 3)) << 3);

  auto STAGE = [&](int c, int kt) {     // 4 gload_lds per wave
    const _Float16* ah = ((kt < 8) ? hF : xF) + (size_t)row0 * 512 + (kt & 7) * 64;
    GLOAD16(ah + aoff0,        &Asm[c][wv * 1024]);
    GLOAD16(ah + aoff0 + 4096, &Asm[c][wv * 1024 + 512]);
    const _Float16* bt = Bimg + ((size_t)(nt * 16 + kt) << 13);
    GLOAD16(bt + (wv * 128 + l) * 8,        &Bsm[c][wv * 1024]);
    GLOAD16(bt + (wv * 128 + 64 + l) * 8,   &Bsm[c][wv * 1024 + 512]);
  };

  // Fragment read bases (fp16-elem offsets).
  const int vA  = (wm * 64 + l15) * 64;           // + ((c8^(l15&7))<<3) + mf*1024
  const int vB0 = wn * 256 + l15 * 8;             // + c8*1024 + nf*128

  f4 acc[4][2];
#pragma unroll
  for (int mf = 0; mf < 4; ++mf)
#pragma unroll
    for (int nf = 0; nf < 2; ++nf)
      acc[mf][nf] = (f4){0.f, 0.f, 0.f, 0.f};

  STAGE(0, 0);
  __syncthreads();                         // publish tile 0

  for (int kt = 0; kt < 16; ++kt) {
    const int c = kt & 1;
    if (kt < 15) STAGE(c ^ 1, kt + 1);     // issue BEFORE compute
#pragma unroll
    for (int kk = 0; kk < 2; ++kk) {
      const int c8 = kk * 4 + lhi;
      const int aoffk = vA + ((c8 ^ (l15 & 7)) << 3);
      h8 af[4], bf[2];
#pragma unroll
      for (int mf = 0; mf < 4; ++mf)
        af[mf] = *(const h8*)&Asm[c][aoffk + mf * 1024];
#pragma unroll
      for (int nf = 0; nf < 2; ++nf)
        bf[nf] = *(const h8*)&Bsm[c][c8 * 1024 + vB0 + nf * 128];
#pragma unroll
      for (int mf = 0; mf < 4; ++mf)
#pragma unroll
        for (int nf = 0; nf < 2; ++nf)
          acc[mf][nf] = __builtin_amdgcn_mfma_f32_16x16x32_f16(af[mf], bf[nf], acc[mf][nf], 0, 0, 0);
    }
    __syncthreads();                       // vmcnt0+lgkm0: tile kt+1 ready, reads of c done
  }

  // Epilogue: e[row] += sum over this wave's 32 cols of fast_tanh(u)*Ve
  float vev[2], biasv[2];
#pragma unroll
  for (int nf = 0; nf < 2; ++nf) {
    int c = nt * 128 + wn * 32 + nf * 16 + l15;
    vev[nf]   = Ve[c];
    biasv[nf] = bias[(size_t)bb * 512 + c];
  }
#pragma unroll
  for (int mf = 0; mf < 4; ++mf) {
#pragma unroll
    for (int j = 0; j < 4; ++j) {
      float s = fast_tanh(acc[mf][0][j] + biasv[0]) * vev[0]
              + fast_tanh(acc[mf][1][j] + biasv[1]) * vev[1];
#pragma unroll
      for (int m = 1; m < 16; m <<= 1) s += __shfl_xor(s, m, 64);
      if (l15 == 0) atomicAdd(&e[row0 + wm * 64 + mf * 16 + lhi * 4 + j], s);
    }
  }
}

// ---------------------------------------------------------------------------
// Fused softmax + context. Block = (b, sc). 512 blocks x 512 threads.
// ---------------------------------------------------------------------------
__global__ __launch_bounds__(512)
void smax_ctx_kernel(const _Float16* __restrict__ hF, const float* __restrict__ e,
                     float* __restrict__ out) {
  const int b  = blockIdx.x >> 2;
  const int sc = blockIdx.x & 3;
  const int t  = threadIdx.x;
  __shared__ float al[512];
  __shared__ float redm[8], reds[8];
  float v = e[(size_t)b * 512 + t];
  float m = v;
#pragma unroll
  for (int d = 1; d < 64; d <<= 1) m = fmaxf(m, __shfl_xor(m, d, 64));
  if ((t & 63) == 0) redm[t >> 6] = m;
  __syncthreads();
  m = redm[0];
#pragma unroll
  for (int i = 1; i < 8; ++i) m = fmaxf(m, redm[i]);
  float ev = __expf(v - m);
  al[t] = ev;
  float s = ev;
#pragma unroll
  for (int d = 1; d < 64; d <<= 1) s += __shfl_xor(s, d, 64);
  if ((t & 63) == 0) reds[t >> 6] = s;
  __syncthreads();
  s = reds[0];
#pragma unroll
  for (int i = 1; i < 8; ++i) s += reds[i];
  const float inv = 1.0f / s;
  const _Float16* hp = hF + ((size_t)b * 512 + sc * 128) * 512 + t;
  float acc = 0.f;
#pragma unroll 4
  for (int q = 0; q < 128; ++q) acc += al[sc * 128 + q] * (float)hp[(size_t)q * 512];
  atomicAdd(&out[(size_t)b * 512 + t], acc * inv);
}

// ---------------------------------------------------------------------------
extern "C" void kernel_launch(void* const* d_in, const int* in_sizes, int n_in,
                              void* d_out, int out_size, void* d_ws, size_t ws_size,
                              hipStream_t stream) {
  const float* h  = (const float*)d_in[0];
  const float* x  = (const float*)d_in[1];
  const float* Ve = (const float*)d_in[2];
  const float* U1 = (const float*)d_in[3];
  const float* U2 = (const float*)d_in[4];
  float* out = (float*)d_out;

  const size_t MB = 1u << 20;
  if (ws_size < 130 * MB) return;   // harness provides >=130MB (verified R6/R7)

  // ws: hF 64MB | xF 64MB | Bimg 1MB | bias 256KB | e 256KB
  _Float16* hF   = (_Float16*)d_ws;
  _Float16* xF   = (_Float16*)((char*)d_ws + 64 * MB);
  _Float16* Bimg = (_Float16*)((char*)d_ws + 128 * MB);
  float*    bias = (float*)((char*)d_ws + 129 * MB);
  float*    e    = (float*)((char*)d_ws + 129 * MB + 256 * 1024);

  hipMemsetAsync(e, 0, 65536 * sizeof(float), stream);
  hipMemsetAsync(d_out, 0, 65536 * sizeof(float), stream);

  cvt2_kernel<<<4096, 256, 0, stream>>>(h, x, hF, xF);
  bsetup3_kernel<<<256, 256, 0, stream>>>(U1, U2, Bimg);
  bias_kernel<<<128, 256, 0, stream>>>(h, U1, bias);
  gemm4_kernel<<<2048, 512, 0, stream>>>(hF, xF, Bimg, bias, Ve, e);
  smax_ctx_kernel<<<512, 512, 0, stream>>>(hF, e, out);
}

// Round 9
// 272.881 us; speedup vs baseline: 1.0635x; 1.0635x over previous
//
#include <hip/hip_runtime.h>
#include <cstdint>
#include <cstddef>

// Problem: B=128, S=512, H=512
//   context[b,h] = sum_s softmax_s( sum_k tanh(u[b,s,k]) Ve[k] ) * h[b,s,h]
//   u = h@U1a^T + x@U2^T + (h_last@U1b^T broadcast over s)
// R9: 128x256 tile, 8 waves x (64x64), TRIPLE-buffered LDS (144 KB), prefetch
//   2 K-tiles ahead with one vmcnt(6)+barrier per K-tile (never drain to 0),
//   setprio'd MFMA clusters. All staging global_load_lds, zero staging VGPRs.

typedef _Float16 h8 __attribute__((ext_vector_type(8)));
typedef float    f4 __attribute__((ext_vector_type(4)));

#define GLOAD16(g, l)                                                          \
  __builtin_amdgcn_global_load_lds(                                            \
      (const __attribute__((address_space(1))) void*)(g),                      \
      (__attribute__((address_space(3))) void*)(l), 16, 0, 0)

__device__ __forceinline__ float fast_tanh(float v) {
  float ex = __expf(2.0f * v);
  return 1.0f - 2.0f / (ex + 1.0f);
}

// ---------------------------------------------------------------------------
// Streaming f32 -> fp16 for BOTH h and x in one launch (grid-stride).
// ---------------------------------------------------------------------------
__global__ __launch_bounds__(256)
void cvt2_kernel(const float* __restrict__ h, const float* __restrict__ x,
                 _Float16* __restrict__ hF, _Float16* __restrict__ xF) {
  const int stride = gridDim.x * 256;
  for (int i = blockIdx.x * 256 + threadIdx.x; i < 8388608; i += stride) {
    const bool isH = i < 4194304;
    const float* p = (isH ? h : x) + ((size_t)(i & 4194303)) * 8;
    _Float16* d = (isH ? hF : xF) + ((size_t)(i & 4194303)) * 8;
    f4 a = *(const f4*)p, b = *(const f4*)(p + 4);
    _Float16 hv[8];
    hv[0]=(_Float16)a[0]; hv[1]=(_Float16)a[1]; hv[2]=(_Float16)a[2]; hv[3]=(_Float16)a[3];
    hv[4]=(_Float16)b[0]; hv[5]=(_Float16)b[1]; hv[6]=(_Float16)b[2]; hv[7]=(_Float16)b[3];
    *(uint4*)d = *(uint4*)hv;
  }
}

// ---------------------------------------------------------------------------
// B image for 128x256 tile / 8-wave layout. 65536 chunks of 16B:
//   g = [nt(2)][kt(16)][wn(4)][nf(4)][kk(2)][lhi(4)][l15(16)]
//   chunk = U[nt*256 + wn*64 + nf*16 + l15][kt*64 + kk*32 + lhi*8 .. +8]
//   U[n][k] = k<512 ? U1[n][k] : U2[n][k-512]
// Per (wn,nf,kk) a wave's 64 lanes read 1 KB CONTIGUOUS -> 0 conflicts,
// and the DMA staging is perfectly linear.
// ---------------------------------------------------------------------------
__global__ void bsetup4_kernel(const float* __restrict__ U1, const float* __restrict__ U2,
                               _Float16* __restrict__ Bimg) {
  int g = blockIdx.x * 256 + threadIdx.x;   // 65536 chunks
  int c   = g & 2047;
  int kt  = (g >> 11) & 15;
  int nt  = g >> 15;
  int l15 = c & 15;
  int lhi = (c >> 4) & 3;
  int kk  = (c >> 6) & 1;
  int nf  = (c >> 7) & 3;
  int wn  = c >> 9;
  int n = nt * 256 + wn * 64 + nf * 16 + l15;
  int k = kt * 64 + kk * 32 + lhi * 8;
  const float* p = (k < 512) ? (U1 + (size_t)n * 1024 + k)
                             : (U2 + (size_t)n * 512 + (k - 512));
  f4 a = *(const f4*)p, b = *(const f4*)(p + 4);
  _Float16 hv[8];
  hv[0]=(_Float16)a[0]; hv[1]=(_Float16)a[1]; hv[2]=(_Float16)a[2]; hv[3]=(_Float16)a[3];
  hv[4]=(_Float16)b[0]; hv[5]=(_Float16)b[1]; hv[6]=(_Float16)b[2]; hv[7]=(_Float16)b[3];
  *(uint4*)(Bimg + (size_t)g * 8) = *(uint4*)hv;
}

// ---------------------------------------------------------------------------
// bias[b][n] = sum_h h[b][S-1][h] * U1[n][512+h]. 128 blocks x 4 waves;
// wave holds its U1b row in registers, loops over b (U1 read once total).
// ---------------------------------------------------------------------------
__global__ __launch_bounds__(256)
void bias2_kernel(const float* __restrict__ hT, const float* __restrict__ U1,
                  float* __restrict__ bias) {
  const int t = threadIdx.x, l = t & 63, w = t >> 6;
  const int n = blockIdx.x * 4 + w;
  const float4* ur = (const float4*)(U1 + (size_t)n * 1024 + 512);
  const float4 u0 = ur[l], u1 = ur[l + 64];
#pragma unroll 4
  for (int b = 0; b < 128; ++b) {
    const float4* hp = (const float4*)(hT + ((size_t)b * 512 + 511) * 512);
    float4 h0 = hp[l], h1 = hp[l + 64];
    float s = u0.x*h0.x + u0.y*h0.y + u0.z*h0.z + u0.w*h0.w
            + u1.x*h1.x + u1.y*h1.y + u1.z*h1.z + u1.w*h1.w;
#pragma unroll
    for (int d = 1; d < 64; d <<= 1) s += __shfl_xor(s, d, 64);
    if (l == 0) bias[(size_t)b * 512 + n] = s;
  }
}

// ---------------------------------------------------------------------------
// Fused GEMM: M=65536, N=512 (2 x BN=256), K=1024, BK=64.
// 512 threads = 8 waves (wm 0..1, wn 0..3), wave tile 64x64 (4x4 frags).
// Triple-buffered: STAGE(kt+2) issued at start of kt into the buffer freed
// at end of kt-1; barrier waits vmcnt(6) = kt+1 landed, kt+2 still flying.
// ---------------------------------------------------------------------------
__global__ __launch_bounds__(512, 2)
void gemm5_kernel(const _Float16* __restrict__ hF, const _Float16* __restrict__ xF,
                  const _Float16* __restrict__ Bimg, const float* __restrict__ bias,
                  const float* __restrict__ Ve, float* __restrict__ e) {
  // XCD-chunked bijective swizzle (1024 = 8*128); nt-siblings adjacent.
  const int bid  = ((int)blockIdx.x & 7) * 128 + ((int)blockIdx.x >> 3);
  const int bm   = bid >> 1;
  const int nt   = bid & 1;
  const int row0 = bm * 128;
  const int bb   = row0 >> 9;
  const int t    = threadIdx.x;
  const int l    = t & 63;
  const int wv   = t >> 6;
  const int wm   = wv >> 2, wn = wv & 3;
  const int l15  = l & 15, lhi = l >> 4;

  __shared__ __align__(16) _Float16 Asm[3][8192];    // 3 x 16 KB
  __shared__ __align__(16) _Float16 Bsm[3][16384];   // 3 x 32 KB

  // A DMA: wave wv stages rows wv*16..+16 (2 instrs), source XOR pre-swizzled.
  const int aoff0 = (wv * 16 + (l >> 3)) * 512 + (((l & 7) ^ (l >> 3)) << 3);

  auto STAGE = [&](int buf, int kt) {   // 6 gload_lds per wave (2 A + 4 B)
    const _Float16* ah = ((kt < 8) ? hF : xF) + (size_t)row0 * 512 + (kt & 7) * 64;
    _Float16* Ad = &Asm[buf][wv * 1024];
    GLOAD16(ah + aoff0,        Ad);
    GLOAD16(ah + aoff0 + 4096, Ad + 512);
    const _Float16* bt = Bimg + ((size_t)(nt * 16 + kt) << 14);
    _Float16* Bd = &Bsm[buf][wv * 512];
#pragma unroll
    for (int j = 0; j < 4; ++j)
      GLOAD16(bt + j * 4096 + wv * 512 + l * 8, Bd + j * 4096);
  };

  // Fragment read bases (fp16-elem offsets), zero loop VALU.
  const int aBase = (wm * 64 + l15) * 64;
  const int b2  = (l15 >> 2) & 1;
  const int lo2 = lhi ^ (l15 & 3);
  const int ak0 = ((((0 ^ b2) << 2) | lo2) << 3);
  const int ak1 = ((((1 ^ b2) << 2) | lo2) << 3);
  const int bBase = wn * 4096 + l * 8;

  f4 acc[4][4];
#pragma unroll
  for (int mf = 0; mf < 4; ++mf)
#pragma unroll
    for (int nf = 0; nf < 4; ++nf)
      acc[mf][nf] = (f4){0.f, 0.f, 0.f, 0.f};

  // Prologue: K0 -> buf0, K1 -> buf1; wait K0 only (K1 stays in flight).
  STAGE(0, 0);
  STAGE(1, 1);
  asm volatile("s_waitcnt vmcnt(6)\n\ts_barrier" ::: "memory");
  __builtin_amdgcn_sched_barrier(0);

  int bc = 0;   // buffer holding K-tile kt
  for (int kt = 0; kt < 16; ++kt) {
    if (kt < 14) {
      int bp = bc + 2; if (bp >= 3) bp -= 3;   // freed at end of kt-1
      STAGE(bp, kt + 2);
    }
    const _Float16* Ab = &Asm[bc][0];
    const _Float16* Bb = &Bsm[bc][0];
#pragma unroll
    for (int kk = 0; kk < 2; ++kk) {
      h8 af[4], bf[4];
      const int akk = kk ? ak1 : ak0;
#pragma unroll
      for (int mf = 0; mf < 4; ++mf)
        af[mf] = *(const h8*)&Ab[aBase + mf * 1024 + akk];
#pragma unroll
      for (int nf = 0; nf < 4; ++nf)
        bf[nf] = *(const h8*)&Bb[bBase + nf * 1024 + kk * 512];
      __builtin_amdgcn_s_setprio(1);
#pragma unroll
      for (int mf = 0; mf < 4; ++mf)
#pragma unroll
        for (int nf = 0; nf < 4; ++nf)
          acc[mf][nf] = __builtin_amdgcn_mfma_f32_16x16x32_f16(af[mf], bf[nf], acc[mf][nf], 0, 0, 0);
      __builtin_amdgcn_s_setprio(0);
    }
    if (kt < 14) {
      asm volatile("s_waitcnt vmcnt(6)\n\ts_barrier" ::: "memory");   // kt+1 landed
      __builtin_amdgcn_sched_barrier(0);
    } else if (kt == 14) {
      asm volatile("s_waitcnt vmcnt(0)\n\ts_barrier" ::: "memory");   // K15 landed
      __builtin_amdgcn_sched_barrier(0);
    }
    bc = bc + 1; if (bc == 3) bc = 0;
  }

  // Epilogue: e[row] += sum over this wave's 64 cols of fast_tanh(u)*Ve
  float vev[4], biasv[4];
#pragma unroll
  for (int nf = 0; nf < 4; ++nf) {
    int c = nt * 256 + wn * 64 + nf * 16 + l15;
    vev[nf]   = Ve[c];
    biasv[nf] = bias[(size_t)bb * 512 + c];
  }
#pragma unroll
  for (int mf = 0; mf < 4; ++mf) {
#pragma unroll
    for (int j = 0; j < 4; ++j) {
      float s = 0.f;
#pragma unroll
      for (int nf = 0; nf < 4; ++nf)
        s += fast_tanh(acc[mf][nf][j] + biasv[nf]) * vev[nf];
#pragma unroll
      for (int m = 1; m < 16; m <<= 1) s += __shfl_xor(s, m, 64);
      if (l15 == 0) atomicAdd(&e[row0 + wm * 64 + mf * 16 + lhi * 4 + j], s);
    }
  }
}

// ---------------------------------------------------------------------------
// Fused softmax + context. Block = (b, sc). 512 blocks x 512 threads.
// ---------------------------------------------------------------------------
__global__ __launch_bounds__(512)
void smax_ctx_kernel(const _Float16* __restrict__ hF, const float* __restrict__ e,
                     float* __restrict__ out) {
  const int b  = blockIdx.x >> 2;
  const int sc = blockIdx.x & 3;
  const int t  = threadIdx.x;
  __shared__ float al[512];
  __shared__ float redm[8], reds[8];
  float v = e[(size_t)b * 512 + t];
  float m = v;
#pragma unroll
  for (int d = 1; d < 64; d <<= 1) m = fmaxf(m, __shfl_xor(m, d, 64));
  if ((t & 63) == 0) redm[t >> 6] = m;
  __syncthreads();
  m = redm[0];
#pragma unroll
  for (int i = 1; i < 8; ++i) m = fmaxf(m, redm[i]);
  float ev = __expf(v - m);
  al[t] = ev;
  float s = ev;
#pragma unroll
  for (int d = 1; d < 64; d <<= 1) s += __shfl_xor(s, d, 64);
  if ((t & 63) == 0) reds[t >> 6] = s;
  __syncthreads();
  s = reds[0];
#pragma unroll
  for (int i = 1; i < 8; ++i) s += reds[i];
  const float inv = 1.0f / s;
  const _Float16* hp = hF + ((size_t)b * 512 + sc * 128) * 512 + t;
  float acc = 0.f;
#pragma unroll 4
  for (int q = 0; q < 128; ++q) acc += al[sc * 128 + q] * (float)hp[(size_t)q * 512];
  atomicAdd(&out[(size_t)b * 512 + t], acc * inv);
}

// ---------------------------------------------------------------------------
extern "C" void kernel_launch(void* const* d_in, const int* in_sizes, int n_in,
                              void* d_out, int out_size, void* d_ws, size_t ws_size,
                              hipStream_t stream) {
  const float* h  = (const float*)d_in[0];
  const float* x  = (const float*)d_in[1];
  const float* Ve = (const float*)d_in[2];
  const float* U1 = (const float*)d_in[3];
  const float* U2 = (const float*)d_in[4];
  float* out = (float*)d_out;

  const size_t MB = 1u << 20;
  if (ws_size < 130 * MB) return;   // harness provides >=130MB (verified R6-R8)

  // ws: hF 64MB | xF 64MB | Bimg 1MB | bias 256KB | e 256KB
  _Float16* hF   = (_Float16*)d_ws;
  _Float16* xF   = (_Float16*)((char*)d_ws + 64 * MB);
  _Float16* Bimg = (_Float16*)((char*)d_ws + 128 * MB);
  float*    bias = (float*)((char*)d_ws + 129 * MB);
  float*    e    = (float*)((char*)d_ws + 129 * MB + 256 * 1024);

  hipMemsetAsync(e, 0, 65536 * sizeof(float), stream);
  hipMemsetAsync(d_out, 0, 65536 * sizeof(float), stream);

  cvt2_kernel<<<4096, 256, 0, stream>>>(h, x, hF, xF);
  bsetup4_kernel<<<256, 256, 0, stream>>>(U1, U2, Bimg);
  bias2_kernel<<<128, 256, 0, stream>>>(h, U1, bias);
  gemm5_kernel<<<1024, 512, 0, stream>>>(hF, xF, Bimg, bias, Ve, e);
  smax_ctx_kernel<<<512, 512, 0, stream>>>(hF, e, out);
}

// Round 10
// 251.431 us; speedup vs baseline: 1.1542x; 1.0853x over previous
//
#include <hip/hip_runtime.h>
#include <cstdint>
#include <cstddef>

// Problem: B=128, S=512, H=512
//   context[b,h] = sum_s softmax_s( sum_k tanh(u[b,s,k]) Ve[k] ) * h[b,s,h]
//   u = h@U1a^T + x@U2^T + (h_last@U1b^T broadcast over s)
// R10: DMA-throughput theory. Only A is staged via global_load_lds (16 KB /
//   K-tile, dbuf, counted vmcnt(4)); B-fragments load DIRECTLY global->VGPR
//   from a fragment-ordered 1 MB image (L2-resident, coalesced 1KB/load),
//   double-buffered in registers. BM=128 BN=128, 4 waves, wave-tile 64x64.

typedef _Float16 h8 __attribute__((ext_vector_type(8)));
typedef float    f4 __attribute__((ext_vector_type(4)));

#define GLOAD16(g, l)                                                          \
  __builtin_amdgcn_global_load_lds(                                            \
      (const __attribute__((address_space(1))) void*)(g),                      \
      (__attribute__((address_space(3))) void*)(l), 16, 0, 0)

#define SB() __builtin_amdgcn_sched_barrier(0)

// Drain oldest VMEM to N (A-DMAs are always the oldest), then barrier.
#define PBAR(N)                                                                \
  do {                                                                         \
    asm volatile("s_waitcnt vmcnt(" #N ") lgkmcnt(0)\n\ts_barrier" ::: "memory"); \
    SB();                                                                      \
  } while (0)

__device__ __forceinline__ float fast_tanh(float v) {
  float ex = __expf(2.0f * v);
  return 1.0f - 2.0f / (ex + 1.0f);
}

// ---------------------------------------------------------------------------
// Streaming f32 -> fp16 for BOTH h and x in one launch (grid-stride).
// ---------------------------------------------------------------------------
__global__ __launch_bounds__(256)
void cvt2_kernel(const float* __restrict__ h, const float* __restrict__ x,
                 _Float16* __restrict__ hF, _Float16* __restrict__ xF) {
  const int stride = gridDim.x * 256;
  for (int i = blockIdx.x * 256 + threadIdx.x; i < 8388608; i += stride) {
    const bool isH = i < 4194304;
    const float* p = (isH ? h : x) + ((size_t)(i & 4194303)) * 8;
    _Float16* d = (isH ? hF : xF) + ((size_t)(i & 4194303)) * 8;
    f4 a = *(const f4*)p, b = *(const f4*)(p + 4);
    _Float16 hv[8];
    hv[0]=(_Float16)a[0]; hv[1]=(_Float16)a[1]; hv[2]=(_Float16)a[2]; hv[3]=(_Float16)a[3];
    hv[4]=(_Float16)b[0]; hv[5]=(_Float16)b[1]; hv[6]=(_Float16)b[2]; hv[7]=(_Float16)b[3];
    *(uint4*)d = *(uint4*)hv;
  }
}

// ---------------------------------------------------------------------------
// B image, fragment-ordered for direct global->register fragment loads.
// 65536 chunks of 16B: g = [nt(4)][kt(16)][wn(2)][nf(4)][kk(2)][lhi(4)][l15(16)]
//   chunk = U[nt*128 + wn*64 + nf*16 + l15][kt*64 + kk*32 + lhi*8 .. +8]
//   U[n][k] = k<512 ? U1[n][k] : U2[n][k-512]
// Wave load for (wn,nf,kk): 64 lanes read 1 KB contiguous (lane l at +l*16B).
// ---------------------------------------------------------------------------
__global__ void bsetup5_kernel(const float* __restrict__ U1, const float* __restrict__ U2,
                               _Float16* __restrict__ Bimg) {
  int g = blockIdx.x * 256 + threadIdx.x;   // 65536 chunks
  int l15 = g & 15;
  int lhi = (g >> 4) & 3;
  int kk  = (g >> 6) & 1;
  int nf  = (g >> 7) & 3;
  int wn  = (g >> 9) & 1;
  int kt  = (g >> 10) & 15;
  int nt  = g >> 14;
  int n = nt * 128 + wn * 64 + nf * 16 + l15;
  int k = kt * 64 + kk * 32 + lhi * 8;
  const float* p = (k < 512) ? (U1 + (size_t)n * 1024 + k)
                             : (U2 + (size_t)n * 512 + (k - 512));
  f4 a = *(const f4*)p, b = *(const f4*)(p + 4);
  _Float16 hv[8];
  hv[0]=(_Float16)a[0]; hv[1]=(_Float16)a[1]; hv[2]=(_Float16)a[2]; hv[3]=(_Float16)a[3];
  hv[4]=(_Float16)b[0]; hv[5]=(_Float16)b[1]; hv[6]=(_Float16)b[2]; hv[7]=(_Float16)b[3];
  *(uint4*)(Bimg + (size_t)g * 8) = *(uint4*)hv;
}

// ---------------------------------------------------------------------------
// bias[b][n] = sum_h h[b][S-1][h] * U1[n][512+h]. U1 read once total.
// ---------------------------------------------------------------------------
__global__ __launch_bounds__(256)
void bias2_kernel(const float* __restrict__ hT, const float* __restrict__ U1,
                  float* __restrict__ bias) {
  const int t = threadIdx.x, l = t & 63, w = t >> 6;
  const int n = blockIdx.x * 4 + w;
  const float4* ur = (const float4*)(U1 + (size_t)n * 1024 + 512);
  const float4 u0 = ur[l], u1 = ur[l + 64];
#pragma unroll 4
  for (int b = 0; b < 128; ++b) {
    const float4* hp = (const float4*)(hT + ((size_t)b * 512 + 511) * 512);
    float4 h0 = hp[l], h1 = hp[l + 64];
    float s = u0.x*h0.x + u0.y*h0.y + u0.z*h0.z + u0.w*h0.w
            + u1.x*h1.x + u1.y*h1.y + u1.z*h1.z + u1.w*h1.w;
#pragma unroll
    for (int d = 1; d < 64; d <<= 1) s += __shfl_xor(s, d, 64);
    if (l == 0) bias[(size_t)b * 512 + n] = s;
  }
}

// ---------------------------------------------------------------------------
// Fused GEMM: M=65536, N=512 (4 x BN=128), K=1024, BK=64.
// 256 threads = 4 waves (wm 0..1, wn 0..1), wave tile 64x64 (4x4 frags).
// A: global_load_lds dbuf, XOR pre-swizzled source. B: direct global->VGPR
// fragment loads, register double-buffer (bE/bO), one K-tile ahead.
// ---------------------------------------------------------------------------
__global__ __launch_bounds__(256, 2)
void gemm6_kernel(const _Float16* __restrict__ hF, const _Float16* __restrict__ xF,
                  const _Float16* __restrict__ Bimg, const float* __restrict__ bias,
                  const float* __restrict__ Ve, float* __restrict__ e) {
  // XCD-chunked bijective swizzle (2048 = 8*256); nt-siblings adjacent.
  const int bid  = ((int)blockIdx.x & 7) * 256 + ((int)blockIdx.x >> 3);
  const int bm   = bid >> 2;
  const int nt   = bid & 3;
  const int row0 = bm * 128;
  const int bb   = row0 >> 9;
  const int t    = threadIdx.x;
  const int l    = t & 63;
  const int wv   = t >> 6;
  const int wm   = wv >> 1, wn = wv & 1;
  const int l15  = l & 15, lhi = l >> 4;

  __shared__ __align__(16) _Float16 Asm[2][8192];   // 2 x 16 KB

  // A DMA: wave wv stages rows wv*32..+32 (4 instrs, 8 rows each);
  // source XOR pre-swizzled, dest linear.
  const int aoff0 = (wv * 32 + (l >> 3)) * 512 + (((l & 7) ^ (l >> 3)) << 3);

  auto STAGEA = [&](int c, int kt) {
    const _Float16* ah = ((kt < 8) ? hF : xF) + (size_t)row0 * 512 + (kt & 7) * 64;
#pragma unroll
    for (int j = 0; j < 4; ++j)
      GLOAD16(ah + aoff0 + j * 4096, &Asm[c][wv * 2048 + j * 512]);
  };

  h8 bE[8], bO[8];   // B fragment double-buffer: [kk*4+nf]
  auto LOADB = [&](h8* b, int kt) {
    const _Float16* bt = Bimg + ((size_t)(nt * 16 + kt) << 13)
                              + (size_t)(wn * 512 + l) * 8;
#pragma unroll
    for (int i = 0; i < 8; ++i)
      b[i] = *(const h8*)(bt + ((i & 3) * 128 + (i >> 2) * 64) * 8);
  };

  // A fragment read bases (fp16-elem offsets), zero loop VALU (R9-verified).
  const int aBase = (wm * 64 + l15) * 64;
  const int b2  = (l15 >> 2) & 1;
  const int lo2 = lhi ^ (l15 & 3);
  const int ak0 = ((((0 ^ b2) << 2) | lo2) << 3);
  const int ak1 = ((((1 ^ b2) << 2) | lo2) << 3);

  f4 acc[4][4];
#pragma unroll
  for (int mf = 0; mf < 4; ++mf)
#pragma unroll
    for (int nf = 0; nf < 4; ++nf)
      acc[mf][nf] = (f4){0.f, 0.f, 0.f, 0.f};

  auto COMPUTE = [&](const _Float16* Ab, const h8* b) {
#pragma unroll
    for (int kk = 0; kk < 2; ++kk) {
      const int akk = kk ? ak1 : ak0;
      h8 af[4];
#pragma unroll
      for (int mf = 0; mf < 4; ++mf)
        af[mf] = *(const h8*)&Ab[aBase + mf * 1024 + akk];
#pragma unroll
      for (int mf = 0; mf < 4; ++mf)
#pragma unroll
        for (int nf = 0; nf < 4; ++nf)
          acc[mf][nf] = __builtin_amdgcn_mfma_f32_16x16x32_f16(af[mf], b[kk * 4 + nf], acc[mf][nf], 0, 0, 0);
    }
  };

  // Prologue: A(0) DMA first (oldest), then B(0) regs; drain A only.
  STAGEA(0, 0); SB();
  LOADB(bE, 0); SB();
  PBAR(4);

  for (int kp = 0; kp < 8; ++kp) {
    const int kt0 = kp * 2;
    // even kt = kt0: compute buf0/bE; stage buf1 + bO for kt0+1
    STAGEA(1, kt0 + 1); SB();
    LOADB(bO, kt0 + 1); SB();
    COMPUTE(&Asm[0][0], bE);
    PBAR(4);                           // A(kt0+1) landed; B(kt0+1) flying
    // odd kt = kt0+1: compute buf1/bO; stage buf0 + bE for kt0+2
    if (kp < 7) {
      STAGEA(0, kt0 + 2); SB();
      LOADB(bE, kt0 + 2); SB();
    }
    COMPUTE(&Asm[1][0], bO);
    if (kp < 7) PBAR(4);               // A(kt0+2) landed; B(kt0+2) flying
  }

  // Epilogue: e[row] += sum over this wave's 64 cols of fast_tanh(u)*Ve
  float vev[4], biasv[4];
#pragma unroll
  for (int nf = 0; nf < 4; ++nf) {
    int c = nt * 128 + wn * 64 + nf * 16 + l15;
    vev[nf]   = Ve[c];
    biasv[nf] = bias[(size_t)bb * 512 + c];
  }
#pragma unroll
  for (int mf = 0; mf < 4; ++mf) {
#pragma unroll
    for (int j = 0; j < 4; ++j) {
      float s = 0.f;
#pragma unroll
      for (int nf = 0; nf < 4; ++nf)
        s += fast_tanh(acc[mf][nf][j] + biasv[nf]) * vev[nf];
#pragma unroll
      for (int m = 1; m < 16; m <<= 1) s += __shfl_xor(s, m, 64);
      if (l15 == 0) atomicAdd(&e[row0 + wm * 64 + mf * 16 + lhi * 4 + j], s);
    }
  }
}

// ---------------------------------------------------------------------------
// Fused softmax + context. Block = (b, sc). 512 blocks x 512 threads.
// ---------------------------------------------------------------------------
__global__ __launch_bounds__(512)
void smax_ctx_kernel(const _Float16* __restrict__ hF, const float* __restrict__ e,
                     float* __restrict__ out) {
  const int b  = blockIdx.x >> 2;
  const int sc = blockIdx.x & 3;
  const int t  = threadIdx.x;
  __shared__ float al[512];
  __shared__ float redm[8], reds[8];
  float v = e[(size_t)b * 512 + t];
  float m = v;
#pragma unroll
  for (int d = 1; d < 64; d <<= 1) m = fmaxf(m, __shfl_xor(m, d, 64));
  if ((t & 63) == 0) redm[t >> 6] = m;
  __syncthreads();
  m = redm[0];
#pragma unroll
  for (int i = 1; i < 8; ++i) m = fmaxf(m, redm[i]);
  float ev = __expf(v - m);
  al[t] = ev;
  float s = ev;
#pragma unroll
  for (int d = 1; d < 64; d <<= 1) s += __shfl_xor(s, d, 64);
  if ((t & 63) == 0) reds[t >> 6] = s;
  __syncthreads();
  s = reds[0];
#pragma unroll
  for (int i = 1; i < 8; ++i) s += reds[i];
  const float inv = 1.0f / s;
  const _Float16* hp = hF + ((size_t)b * 512 + sc * 128) * 512 + t;
  float acc = 0.f;
#pragma unroll 4
  for (int q = 0; q < 128; ++q) acc += al[sc * 128 + q] * (float)hp[(size_t)q * 512];
  atomicAdd(&out[(size_t)b * 512 + t], acc * inv);
}

// ---------------------------------------------------------------------------
extern "C" void kernel_launch(void* const* d_in, const int* in_sizes, int n_in,
                              void* d_out, int out_size, void* d_ws, size_t ws_size,
                              hipStream_t stream) {
  const float* h  = (const float*)d_in[0];
  const float* x  = (const float*)d_in[1];
  const float* Ve = (const float*)d_in[2];
  const float* U1 = (const float*)d_in[3];
  const float* U2 = (const float*)d_in[4];
  float* out = (float*)d_out;

  const size_t MB = 1u << 20;
  if (ws_size < 130 * MB) return;   // harness provides >=130MB (verified R6-R9)

  // ws: hF 64MB | xF 64MB | Bimg 1MB | bias 256KB | e 256KB
  _Float16* hF   = (_Float16*)d_ws;
  _Float16* xF   = (_Float16*)((char*)d_ws + 64 * MB);
  _Float16* Bimg = (_Float16*)((char*)d_ws + 128 * MB);
  float*    bias = (float*)((char*)d_ws + 129 * MB);
  float*    e    = (float*)((char*)d_ws + 129 * MB + 256 * 1024);

  hipMemsetAsync(e, 0, 65536 * sizeof(float), stream);
  hipMemsetAsync(d_out, 0, 65536 * sizeof(float), stream);

  cvt2_kernel<<<4096, 256, 0, stream>>>(h, x, hF, xF);
  bsetup5_kernel<<<256, 256, 0, stream>>>(U1, U2, Bimg);
  bias2_kernel<<<128, 256, 0, stream>>>(h, U1, bias);
  gemm6_kernel<<<2048, 256, 0, stream>>>(hF, xF, Bimg, bias, Ve, e);
  smax_ctx_kernel<<<512, 512, 0, stream>>>(hF, e, out);
}